// Round 2
// baseline (643.837 us; speedup 1.0000x reference)
//
#include <hip/hip_runtime.h>
#include <math.h>

#define NROWS 65536
#define DIM   512
#define NCLS  64

// ws layout (4-byte words):
//   0         lossAcc (f32)
//   1         accAcc  (f32)
//   2..66     p2[64]        (f32)
//   66..130   counts[64]    (i32)
//   130..194  cursors[64]   (i32)
//   194..258  offsets[64]   (i32)
//   260..33028            protoSum[64*512] (f32)  [zeroed]
//   33028..98564          perm[65536] (i32); later reused as protoT[512*64]
#define WS_P2       2
#define WS_COUNTS   66
#define WS_CURSORS  130
#define WS_OFFSETS  194
#define WS_PROTOSUM 260
#define WS_PERM     (260 + 32768)
#define MEMSET_WORDS (WS_PERM)   // zero everything up to perm

// ---------------- histogram ----------------
__global__ __launch_bounds__(256) void k_hist(const int* __restrict__ labels,
                                              int* __restrict__ counts) {
    __shared__ int h[NCLS];
    int t = threadIdx.x;
    if (t < NCLS) h[t] = 0;
    __syncthreads();
    int i = blockIdx.x * 256 + t;
    atomicAdd(&h[labels[i]], 1);
    __syncthreads();
    if (t < NCLS) atomicAdd(&counts[t], h[t]);
}

// ---------------- prefix sum: single-wave shfl scan ----------------
__global__ __launch_bounds__(64) void k_prefix(const int* __restrict__ counts,
                                               int* __restrict__ offsets,
                                               int* __restrict__ cursors) {
    int t = threadIdx.x;   // 0..63, one wave
    int v = counts[t];
    int inc = v;
#pragma unroll
    for (int off = 1; off < 64; off <<= 1) {
        int o = __shfl_up(inc, off, 64);
        if (t >= off) inc += o;
    }
    int excl = inc - v;
    offsets[t] = excl;
    cursors[t] = excl;
}

// ---------------- scatter row indices into class buckets ----------------
__global__ __launch_bounds__(256) void k_scatter(const int* __restrict__ labels,
                                                 int* __restrict__ cursors,
                                                 int* __restrict__ perm) {
    int i = blockIdx.x * 256 + threadIdx.x;
    int l = labels[i];
    int pos = atomicAdd(&cursors[l], 1);
    perm[pos] = i;
}

// ---------------- per-class partial sums (gathered, coalesced) ----------
// grid = 64 classes * 4 dim-chunks * 4 row-splits = 1024 blocks
// block = 256 threads = 2 row-groups x 128 dim-lanes
__global__ __launch_bounds__(256) void k_proto(const float* __restrict__ emb,
                                               const int* __restrict__ counts,
                                               const int* __restrict__ offsets,
                                               const int* __restrict__ perm,
                                               float* __restrict__ protoSum) {
    int c    = blockIdx.x >> 4;
    int sub  = blockIdx.x & 15;
    int dc   = sub & 3;       // dim chunk (128 dims)
    int rs   = sub >> 2;      // row split (0..3)
    int dl   = threadIdx.x & 127;
    int g    = threadIdx.x >> 7;   // 0..1  (wave-uniform)
    int d    = dc * 128 + dl;
    int cnt  = counts[c];
    int base = offsets[c];

    float acc = 0.f;
#pragma unroll 4
    for (int i = rs * 2 + g; i < cnt; i += 8) {
        int r = perm[base + i];                 // wave-uniform -> s_load
        acc += emb[(size_t)r * DIM + d];        // 512B contiguous per 2 waves
    }

    __shared__ float red[256];
    red[threadIdx.x] = acc;
    __syncthreads();
    if (threadIdx.x < 128) {
        float s = red[threadIdx.x] + red[threadIdx.x + 128];
        atomicAdd(&protoSum[c * DIM + dc * 128 + threadIdx.x], s);
    }
}

// ---------------- normalize + transpose + p2 ----------------
// grid = 64 (one block per class), block = 512
__global__ __launch_bounds__(512) void k_protofin(const float* __restrict__ protoSum,
                                                  const int* __restrict__ counts,
                                                  float* __restrict__ protoT,
                                                  float* __restrict__ p2) {
    int c = blockIdx.x;
    int t = threadIdx.x;     // = dim
    float mean = protoSum[c * DIM + t] / (float)counts[c];
    protoT[t * NCLS + c] = mean;
    float sq = mean * mean;
#pragma unroll
    for (int off = 32; off > 0; off >>= 1) sq += __shfl_down(sq, off, 64);
    __shared__ float red[8];
    int wid = t >> 6;
    if ((t & 63) == 0) red[wid] = sq;
    __syncthreads();
    if (t == 0) {
        float s = 0.f;
#pragma unroll
        for (int w = 0; w < 8; ++w) s += red[w];
        p2[c] = s;
    }
}

// ---------------- main: distances + log-softmax + argmax + reduce ----------
// grid = 1024 blocks, block = 256 = 64 rows x 4 class-groups (16 classes each)
#define RB 64
__global__ __launch_bounds__(256) void k_logits(const float* __restrict__ emb,
                                                const int* __restrict__ labels,
                                                const float* __restrict__ protoT,
                                                const float* __restrict__ p2,
                                                float* __restrict__ lossAcc,
                                                float* __restrict__ accAcc) {
    int t  = threadIdx.x;
    int rl = t & 63;          // row within block (= lane)
    int cg = t >> 6;          // class group 0..3 (wave-uniform)
    int row = blockIdx.x * RB + rl;

    const float4* rp = (const float4*)(emb + (size_t)row * DIM);
    const float* pbase = protoT + cg * 16;

    float acc[16];
#pragma unroll
    for (int c = 0; c < 16; ++c) acc[c] = 0.f;
    float e2 = 0.f;

    for (int ch = 0; ch < DIM / 32; ++ch) {
        float4 b[8];
#pragma unroll
        for (int k = 0; k < 8; ++k) b[k] = rp[ch * 8 + k];
#pragma unroll
        for (int k = 0; k < 8; ++k) {
            float ev;
            const float* pr;
#pragma unroll
            for (int j = 0; j < 4; ++j) {
                ev = (j == 0) ? b[k].x : (j == 1) ? b[k].y : (j == 2) ? b[k].z : b[k].w;
                e2 += ev * ev;
                pr = pbase + (size_t)(ch * 32 + k * 4 + j) * NCLS;  // uniform -> s_load
#pragma unroll
                for (int c = 0; c < 16; ++c) acc[c] += ev * pr[c];
            }
        }
    }

    // logits for this thread's 16 classes -> LDS
    __shared__ float lgS[RB][NCLS + 1];
#pragma unroll
    for (int c = 0; c < 16; ++c) {
        float d2 = e2 + p2[cg * 16 + c] - 2.f * acc[c];
        d2 = fmaxf(d2, 1e-12f);
        lgS[rl][cg * 16 + c] = -sqrtf(d2);
    }
    __syncthreads();

    // wave 0: one full row per lane
    if (t < 64) {
        int lab = labels[blockIdx.x * RB + t];
        float m = -INFINITY;
        int bi = 0;
#pragma unroll 8
        for (int c = 0; c < NCLS; ++c) {
            float v = lgS[t][c];
            if (v > m) { m = v; bi = c; }   // strict > = first-max (jnp.argmax)
        }
        float se = 0.f;
#pragma unroll 8
        for (int c = 0; c < NCLS; ++c) se += __expf(lgS[t][c] - m);
        float nll = __logf(se) + m - lgS[t][lab];
        float correct = (bi == lab) ? 1.f : 0.f;
#pragma unroll
        for (int off = 32; off > 0; off >>= 1) {
            nll     += __shfl_down(nll, off, 64);
            correct += __shfl_down(correct, off, 64);
        }
        if (t == 0) {
            atomicAdd(lossAcc, nll);
            atomicAdd(accAcc, correct);
        }
    }
}

// ---------------- finalize ----------------
__global__ void k_final(const float* __restrict__ lossAcc,
                        const float* __restrict__ accAcc,
                        float* __restrict__ out) {
    if (threadIdx.x == 0 && blockIdx.x == 0) {
        out[0] = lossAcc[0] * (1.f / NROWS);
        out[1] = accAcc[0] * (1.f / NROWS);
    }
}

extern "C" void kernel_launch(void* const* d_in, const int* in_sizes, int n_in,
                              void* d_out, int out_size, void* d_ws, size_t ws_size,
                              hipStream_t stream) {
    const float* emb    = (const float*)d_in[0];
    const int*   labels = (const int*)d_in[1];
    float* out = (float*)d_out;

    float* wsf = (float*)d_ws;
    int*   wsi = (int*)d_ws;
    float* lossAcc  = wsf + 0;
    float* accAcc   = wsf + 1;
    float* p2       = wsf + WS_P2;
    int*   counts   = wsi + WS_COUNTS;
    int*   cursors  = wsi + WS_CURSORS;
    int*   offsets  = wsi + WS_OFFSETS;
    float* protoSum = wsf + WS_PROTOSUM;
    int*   perm     = wsi + WS_PERM;
    float* protoT   = wsf + WS_PERM;   // reuses perm region after k_proto

    // zero accumulators / counts / cursors / protoSum (ws is 0xAA-poisoned)
    hipMemsetAsync(d_ws, 0, MEMSET_WORDS * sizeof(int), stream);

    k_hist<<<NROWS / 256, 256, 0, stream>>>(labels, counts);
    k_prefix<<<1, 64, 0, stream>>>(counts, offsets, cursors);
    k_scatter<<<NROWS / 256, 256, 0, stream>>>(labels, cursors, perm);
    k_proto<<<NCLS * 16, 256, 0, stream>>>(emb, counts, offsets, perm, protoSum);
    k_protofin<<<NCLS, 512, 0, stream>>>(protoSum, counts, protoT, p2);
    k_logits<<<NROWS / RB, 256, 0, stream>>>(emb, labels, protoT, p2,
                                             lossAcc, accAcc);
    k_final<<<1, 64, 0, stream>>>(lossAcc, accAcc, out);
}

// Round 3
// 407.237 us; speedup vs baseline: 1.5810x; 1.5810x over previous
//
#include <hip/hip_runtime.h>
#include <math.h>

#define NROWS 65536
#define DIM   512
#define NCLS  64

typedef __attribute__((ext_vector_type(4))) float f32x4;
typedef __attribute__((ext_vector_type(8))) short s16x8;

// ws layout (4-byte words):
//   [0 .. 32768)    protoSum[64][512] f32   (zeroed by memset)
//   [32768..32832)  counts[64] i32          (zeroed)
//   32832 lossAcc   32833 accAcc            (zeroed)
//   [32836..32900)  p2[64] f32
//   [32848-> use 32912..49296) pB[64][512] bf16 (ushort), 16B-aligned
#define WS_PROTOSUM 0
#define WS_COUNTS   32768
#define WS_LOSS     32832
#define WS_ACC      32833
#define WS_P2       32836
#define WS_PB       32912            // word offset; byte 131648, 16B aligned
#define MEMSET_WORDS 32834           // protoSum + counts + loss + acc

static __device__ __forceinline__ unsigned short f2bf(float f) {
    unsigned int u = __float_as_uint(f);
    u += 0x7FFF + ((u >> 16) & 1);   // RNE
    return (unsigned short)(u >> 16);
}
static __device__ __forceinline__ float bf2f(unsigned short h) {
    return __uint_as_float(((unsigned int)h) << 16);
}

// ---------------- prototypes: fused count + per-class sum ----------------
// grid = 4 dim-chunks x 64 row-splits = 256 blocks; block = 512 threads
// thread = (row-group g = t>>7 in 0..3) x (dim lane dl = t&127)
__global__ __launch_bounds__(512) void k_proto(const float* __restrict__ emb,
                                               const int* __restrict__ labels,
                                               float* __restrict__ protoSum,
                                               int* __restrict__ counts) {
    __shared__ float sums[NCLS][128];   // 32 KB
    __shared__ int   labs[1024];        // 4 KB
    __shared__ int   cntS[NCLS];

    int t  = threadIdx.x;
    int dc = blockIdx.x & 3;
    int s  = blockIdx.x >> 2;
    int dl = t & 127;
    int g  = t >> 7;               // wave-uniform (2 waves per g)
    int r0 = s * 1024;

    // zero LDS accumulators
    for (int i = t; i < NCLS * 128; i += 512) ((float*)sums)[i] = 0.f;
    if (t < NCLS) cntS[t] = 0;
    // stage labels for this block's 1024 rows (coalesced)
    labs[t]       = labels[r0 + t];
    labs[t + 512] = labels[r0 + t + 512];
    __syncthreads();

    const float* ebase = emb + (size_t)r0 * DIM + dc * 128 + dl;
    for (int i = 0; i < 256; i += 8) {
#pragma unroll
        for (int u = 0; u < 8; ++u) {
            int rl  = (i + u) * 4 + g;
            int lab = labs[rl];                       // broadcast read
            float v = ebase[(size_t)rl * DIM];        // 512B contig / 2 waves
            atomicAdd(&sums[lab][dl], v);             // ds_add, 2-way banks
            if (dl == 0) atomicAdd(&cntS[lab], 1);
        }
    }
    __syncthreads();

    // flush partial sums to global (coalesced atomic adds)
    for (int idx = t; idx < NCLS * 128; idx += 512) {
        int c = idx >> 7, d = idx & 127;
        atomicAdd(&protoSum[(size_t)c * DIM + dc * 128 + d], sums[c][d]);
    }
    if (dc == 0 && t < NCLS) atomicAdd(&counts[t], cntS[t]);
}

// ---------------- finalize prototypes: mean -> bf16 B[n][k], p2 -----------
// grid = 64 (class per block), block = 512 (dim per thread)
__global__ __launch_bounds__(512) void k_protofin(const float* __restrict__ protoSum,
                                                  const int* __restrict__ counts,
                                                  unsigned short* __restrict__ pB,
                                                  float* __restrict__ p2) {
    int c = blockIdx.x, d = threadIdx.x;
    float mean = protoSum[(size_t)c * DIM + d] / (float)counts[c];
    unsigned short mb = f2bf(mean);
    pB[(size_t)c * DIM + d] = mb;       // B stored [n][k] for MFMA B-frags
    float mf = bf2f(mb);
    float sq = mf * mf;
#pragma unroll
    for (int o = 32; o > 0; o >>= 1) sq += __shfl_down(sq, o, 64);
    __shared__ float red[8];
    if ((d & 63) == 0) red[d >> 6] = sq;
    __syncthreads();
    if (d == 0) {
        float ss = 0.f;
#pragma unroll
        for (int w = 0; w < 8; ++w) ss += red[w];
        p2[c] = ss;
    }
}

// ---------------- main: bf16 MFMA distances + softmax + reduce ------------
// grid = 512 blocks x 256 thr; block = 128 rows; wave w owns rows w*32..+31
// wave tile = 32 rows x 64 cols = 2 m-tiles x 4 n-tiles of 16x16x32 MFMAs
__global__ __launch_bounds__(256) void k_logits(const float* __restrict__ emb,
                                                const int* __restrict__ labels,
                                                const unsigned short* __restrict__ pB,
                                                const float* __restrict__ p2,
                                                float* __restrict__ lossAcc,
                                                float* __restrict__ accAcc) {
    __shared__ __align__(16) unsigned short Asm[128 * 40];  // 32 k/row, pad 40
    __shared__ float e2s[128];

    int t     = threadIdx.x;
    int lane  = t & 63;
    int wv    = t >> 6;
    int quad  = lane >> 4;
    int l15   = lane & 15;
    int rbase = blockIdx.x * 128;

    f32x4 acc[2][4];
#pragma unroll
    for (int mt = 0; mt < 2; ++mt)
#pragma unroll
        for (int nt = 0; nt < 4; ++nt) acc[mt][nt] = (f32x4){0.f, 0.f, 0.f, 0.f};

    float e2a[4] = {0.f, 0.f, 0.f, 0.f};
    const float4* emb4 = (const float4*)(emb + (size_t)rbase * DIM);

    for (int kc = 0; kc < 16; ++kc) {
        // ---- stage: global fp32 -> bf16 LDS (f = t + 256k; row=f>>3, j=f&7)
        float4 gbuf[4];
#pragma unroll
        for (int k = 0; k < 4; ++k) {
            int f = t + 256 * k;
            int row = f >> 3, j = f & 7;
            gbuf[k] = emb4[(size_t)row * (DIM / 4) + kc * 8 + j];
        }
        // B-fragments for this k-chunk (independent of LDS -> issue early)
        s16x8 bf[4];
#pragma unroll
        for (int nt = 0; nt < 4; ++nt) {
            size_t off = (size_t)(nt * 16 + l15) * DIM + kc * 32 + quad * 8;
            bf[nt] = *(const s16x8*)(pB + off);
        }
#pragma unroll
        for (int k = 0; k < 4; ++k) {
            float4 gv = gbuf[k];
            e2a[k] += gv.x * gv.x + gv.y * gv.y + gv.z * gv.z + gv.w * gv.w;
            int f = t + 256 * k;
            int row = f >> 3, j = f & 7;
            ushort4 h;
            h.x = f2bf(gv.x); h.y = f2bf(gv.y); h.z = f2bf(gv.z); h.w = f2bf(gv.w);
            *(ushort4*)&Asm[row * 40 + j * 4] = h;   // ds_write_b64
        }
        __syncthreads();
        // ---- compute: A-frags from LDS, 8 MFMAs
        s16x8 a0 = *(const s16x8*)&Asm[(wv * 32 + l15) * 40 + quad * 8];
        s16x8 a1 = *(const s16x8*)&Asm[(wv * 32 + 16 + l15) * 40 + quad * 8];
#pragma unroll
        for (int nt = 0; nt < 4; ++nt) {
            acc[0][nt] = __builtin_amdgcn_mfma_f32_16x16x32_bf16(a0, bf[nt], acc[0][nt], 0, 0, 0);
            acc[1][nt] = __builtin_amdgcn_mfma_f32_16x16x32_bf16(a1, bf[nt], acc[1][nt], 0, 0, 0);
        }
        __syncthreads();
    }

    // ---- flush e2 (8 lanes share a row: xor-reduce 1,2,4)
#pragma unroll
    for (int k = 0; k < 4; ++k) {
        float v = e2a[k];
        v += __shfl_xor(v, 1, 64);
        v += __shfl_xor(v, 2, 64);
        v += __shfl_xor(v, 4, 64);
        if ((lane & 7) == 0) e2s[wv * 8 + 32 * k + (lane >> 3)] = v;
    }
    __syncthreads();

    // ---- epilogue: per-row softmax/argmax over the 64 cols
    // C/D layout: col = nt*16 + l15, row = mt*16 + quad*4 + reg
    float nlls = 0.f, corr = 0.f;
#pragma unroll
    for (int mt = 0; mt < 2; ++mt) {
#pragma unroll
        for (int reg = 0; reg < 4; ++reg) {
            int rloc = wv * 32 + mt * 16 + quad * 4 + reg;
            float e2v = e2s[rloc];
            float lg[4];
#pragma unroll
            for (int nt = 0; nt < 4; ++nt) {
                float d2 = e2v + p2[nt * 16 + l15] - 2.f * acc[mt][nt][reg];
                d2 = fmaxf(d2, 1e-12f);
                lg[nt] = -sqrtf(d2);
            }
            float mv = lg[0]; int mc = l15;
#pragma unroll
            for (int nt = 1; nt < 4; ++nt) {
                int c = nt * 16 + l15;
                if (lg[nt] > mv) { mv = lg[nt]; mc = c; }
            }
#pragma unroll
            for (int o = 1; o < 16; o <<= 1) {
                float mo = __shfl_xor(mv, o, 64);
                int   co = __shfl_xor(mc, o, 64);
                if (mo > mv || (mo == mv && co < mc)) { mv = mo; mc = co; }
            }
            int lab = labels[rbase + rloc];
            float se = 0.f, ll = 0.f;
#pragma unroll
            for (int nt = 0; nt < 4; ++nt) se += __expf(lg[nt] - mv);
            if ((lab & 15) == l15) ll = lg[lab >> 4];
#pragma unroll
            for (int o = 1; o < 16; o <<= 1) {
                se += __shfl_xor(se, o, 64);
                ll += __shfl_xor(ll, o, 64);
            }
            if (l15 == 0) {
                nlls += __logf(se) + mv - ll;
                corr += (mc == lab) ? 1.f : 0.f;
            }
        }
    }
#pragma unroll
    for (int o = 1; o < 64; o <<= 1) {
        nlls += __shfl_xor(nlls, o, 64);
        corr += __shfl_xor(corr, o, 64);
    }
    __shared__ float rb[8];
    if (lane == 0) { rb[wv] = nlls; rb[4 + wv] = corr; }
    __syncthreads();
    if (t == 0) {
        atomicAdd(lossAcc, rb[0] + rb[1] + rb[2] + rb[3]);
        atomicAdd(accAcc, rb[4] + rb[5] + rb[6] + rb[7]);
    }
}

// ---------------- finalize ----------------
__global__ void k_final(const float* __restrict__ lossAcc,
                        const float* __restrict__ accAcc,
                        float* __restrict__ out) {
    if (threadIdx.x == 0 && blockIdx.x == 0) {
        out[0] = lossAcc[0] * (1.f / NROWS);
        out[1] = accAcc[0] * (1.f / NROWS);
    }
}

extern "C" void kernel_launch(void* const* d_in, const int* in_sizes, int n_in,
                              void* d_out, int out_size, void* d_ws, size_t ws_size,
                              hipStream_t stream) {
    const float* emb    = (const float*)d_in[0];
    const int*   labels = (const int*)d_in[1];
    float* out = (float*)d_out;

    float* wsf = (float*)d_ws;
    int*   wsi = (int*)d_ws;
    float*          protoSum = wsf + WS_PROTOSUM;
    int*            counts   = wsi + WS_COUNTS;
    float*          lossAcc  = wsf + WS_LOSS;
    float*          accAcc   = wsf + WS_ACC;
    float*          p2       = wsf + WS_P2;
    unsigned short* pB       = (unsigned short*)(wsf + WS_PB);

    hipMemsetAsync(d_ws, 0, MEMSET_WORDS * sizeof(int), stream);

    k_proto<<<256, 512, 0, stream>>>(emb, labels, protoSum, counts);
    k_protofin<<<NCLS, 512, 0, stream>>>(protoSum, counts, pB, p2);
    k_logits<<<NROWS / 128, 256, 0, stream>>>(emb, labels, pB, p2, lossAcc, accAcc);
    k_final<<<1, 64, 0, stream>>>(lossAcc, accAcc, out);
}

// Round 4
// 273.614 us; speedup vs baseline: 2.3531x; 1.4884x over previous
//
#include <hip/hip_runtime.h>
#include <math.h>

#define NROWS 65536
#define DIM   512
#define NCLS  64
#define CCAP  1280   // per-class bucket capacity (mean 1024, sd ~32 -> 8 sigma)

typedef __attribute__((ext_vector_type(4))) float f32x4;
typedef __attribute__((ext_vector_type(8))) short s16x8;

// ws layout (4-byte words):
//   [0..32768)      protoSum[64][512] f32   (zeroed)
//   [32768..32832)  cursors[64] i32         (zeroed; == counts after scatter)
//   32832 lossAcc   32833 accAcc            (zeroed)
//   [32836..32900)  p2[64] f32
//   [32912..114832) perm[64*1280] i32 ; pB bf16[64*512] overlays its start
//                   after k_psum (byte 131648, 16B aligned)
#define WS_PROTOSUM 0
#define WS_CURSORS  32768
#define WS_LOSS     32832
#define WS_ACC      32833
#define WS_P2       32836
#define WS_PERM     32912
#define WS_PB       32912
#define MEMSET_WORDS 32834

static __device__ __forceinline__ unsigned short f2bf(float f) {
    unsigned int u = __float_as_uint(f);
    u += 0x7FFF + ((u >> 16) & 1);   // RNE
    return (unsigned short)(u >> 16);
}
static __device__ __forceinline__ float bf2f(unsigned short h) {
    return __uint_as_float(((unsigned int)h) << 16);
}

// ---------------- scatter rows into fixed-stride class buckets ------------
// 256 blocks x 256 thr; block-local ranks via LDS atomics, one global
// atomic per class per block to reserve a range.
__global__ __launch_bounds__(256) void k_scatter(const int* __restrict__ labels,
                                                 int* __restrict__ cursors,
                                                 int* __restrict__ perm) {
    __shared__ int lh[NCLS], lb[NCLS];
    int t = threadIdx.x;
    if (t < NCLS) lh[t] = 0;
    __syncthreads();
    int i = blockIdx.x * 256 + t;
    int lab = labels[i];
    int rank = atomicAdd(&lh[lab], 1);
    __syncthreads();
    if (t < NCLS) lb[t] = atomicAdd(&cursors[t], lh[t]);
    __syncthreads();
    int pos = lb[lab] + rank;
    if (pos < CCAP) perm[lab * CCAP + pos] = i;
}

// ---------------- per-class partial sums, register accumulation ----------
// grid = 64 classes x 4 dim-chunks x 8 row-splits = 2048 blocks (8/CU, 100% occ)
// block = 256 thr = 4 row-groups (g) x 64 dim-lanes (float2 each = 128 dims)
__global__ __launch_bounds__(256) void k_psum(const float* __restrict__ emb,
                                              const int* __restrict__ cursors,
                                              const int* __restrict__ perm,
                                              float* __restrict__ protoSum) {
    __shared__ int permS[CCAP];
    __shared__ float2 red[256];
    int t   = threadIdx.x;
    int c   = blockIdx.x >> 5;
    int sub = blockIdx.x & 31;
    int dc  = sub & 3;        // dim chunk (128 dims)
    int rs  = sub >> 2;       // row split 0..7
    int tl  = t & 63;
    int g   = t >> 6;         // 0..3 (wave-uniform)

    int cnt = cursors[c];
    int n = (cnt < CCAP) ? cnt : CCAP;
    for (int i = t; i < n; i += 256) permS[i] = perm[c * CCAP + i];
    __syncthreads();

    const float2* eb = (const float2*)emb + dc * 64 + tl;
    float2 acc; acc.x = 0.f; acc.y = 0.f;
#pragma unroll 4
    for (int i = rs * 4 + g; i < n; i += 32) {
        int r = permS[i];                       // LDS broadcast
        float2 v = eb[(size_t)r * 256];         // 512B contiguous per wave
        acc.x += v.x; acc.y += v.y;
    }
    red[t] = acc;
    __syncthreads();
    if (t < 64) {
        float2 a = red[t], b = red[t + 64], cc = red[t + 128], d = red[t + 192];
        float sx = a.x + b.x + cc.x + d.x;
        float sy = a.y + b.y + cc.y + d.y;
        atomicAdd(&protoSum[(size_t)c * DIM + dc * 128 + t * 2], sx);
        atomicAdd(&protoSum[(size_t)c * DIM + dc * 128 + t * 2 + 1], sy);
    }
}

// ---------------- finalize prototypes: mean -> bf16 B[n][k], p2 -----------
__global__ __launch_bounds__(512) void k_protofin(const float* __restrict__ protoSum,
                                                  const int* __restrict__ cursors,
                                                  unsigned short* __restrict__ pB,
                                                  float* __restrict__ p2) {
    int c = blockIdx.x, d = threadIdx.x;
    float mean = protoSum[(size_t)c * DIM + d] / (float)cursors[c];
    unsigned short mb = f2bf(mean);
    pB[(size_t)c * DIM + d] = mb;       // [n][k] for MFMA B-frags
    float mf = bf2f(mb);
    float sq = mf * mf;
#pragma unroll
    for (int o = 32; o > 0; o >>= 1) sq += __shfl_down(sq, o, 64);
    __shared__ float red[8];
    if ((d & 63) == 0) red[d >> 6] = sq;
    __syncthreads();
    if (d == 0) {
        float ss = 0.f;
#pragma unroll
        for (int w = 0; w < 8; ++w) ss += red[w];
        p2[c] = ss;
    }
}

// ---------------- main: bf16 MFMA distances + softmax + reduce ------------
// grid = 1024 blocks x 256 thr; 64 rows/block; wave wv owns m-tile rows
// wv*16..+15 x all 64 cols (4 n-tiles). Register prefetch across barrier.
#define LROWS 64
__global__ __launch_bounds__(256) void k_logits(const float* __restrict__ emb,
                                                const int* __restrict__ labels,
                                                const unsigned short* __restrict__ pB,
                                                const float* __restrict__ p2,
                                                float* __restrict__ lossAcc,
                                                float* __restrict__ accAcc) {
    __shared__ __align__(16) unsigned short Asm[LROWS * 36]; // stride 36: 2-way max
    __shared__ float e2s[LROWS];
    __shared__ float rb[8];

    int t    = threadIdx.x;
    int lane = t & 63;
    int wv   = t >> 6;
    int quad = lane >> 4;
    int l15  = lane & 15;
    int rbase = blockIdx.x * LROWS;

    f32x4 acc[4];
#pragma unroll
    for (int nt = 0; nt < 4; ++nt) acc[nt] = (f32x4){0.f, 0.f, 0.f, 0.f};
    float e2a0 = 0.f, e2a1 = 0.f;

    const float4* emb4 = (const float4*)(emb + (size_t)rbase * DIM);
    int row0 = t >> 3, j0 = t & 7;   // f = t       -> rows 0..31
    int row1 = 32 + row0;            // f = t + 256 -> rows 32..63

    float4 g0 = emb4[(size_t)row0 * 128 + j0];
    float4 g1 = emb4[(size_t)row1 * 128 + j0];

    for (int kc = 0; kc < 16; ++kc) {
        // convert + e2 + stage to LDS
        e2a0 += g0.x * g0.x + g0.y * g0.y + g0.z * g0.z + g0.w * g0.w;
        e2a1 += g1.x * g1.x + g1.y * g1.y + g1.z * g1.z + g1.w * g1.w;
        ushort4 h0, h1;
        h0.x = f2bf(g0.x); h0.y = f2bf(g0.y); h0.z = f2bf(g0.z); h0.w = f2bf(g0.w);
        h1.x = f2bf(g1.x); h1.y = f2bf(g1.y); h1.z = f2bf(g1.z); h1.w = f2bf(g1.w);
        *(ushort4*)&Asm[row0 * 36 + j0 * 4] = h0;
        *(ushort4*)&Asm[row1 * 36 + j0 * 4] = h1;
        __syncthreads();

        // B-fragments (global, L2-resident 64KB)
        s16x8 bf[4];
#pragma unroll
        for (int nt = 0; nt < 4; ++nt)
            bf[nt] = *(const s16x8*)(pB + (size_t)(nt * 16 + l15) * DIM + kc * 32 + quad * 8);
        // A-fragment
        s16x8 a = *(const s16x8*)&Asm[(wv * 16 + l15) * 36 + quad * 8];
        // prefetch next chunk (in flight across the barrier + MFMAs)
        if (kc + 1 < 16) {
            g0 = emb4[(size_t)row0 * 128 + (kc + 1) * 8 + j0];
            g1 = emb4[(size_t)row1 * 128 + (kc + 1) * 8 + j0];
        }
        __syncthreads();
#pragma unroll
        for (int nt = 0; nt < 4; ++nt)
            acc[nt] = __builtin_amdgcn_mfma_f32_16x16x32_bf16(a, bf[nt], acc[nt], 0, 0, 0);
    }

    // flush e2 (8 consecutive lanes share a row)
    float v0 = e2a0;
    v0 += __shfl_xor(v0, 1, 64); v0 += __shfl_xor(v0, 2, 64); v0 += __shfl_xor(v0, 4, 64);
    float v1 = e2a1;
    v1 += __shfl_xor(v1, 1, 64); v1 += __shfl_xor(v1, 2, 64); v1 += __shfl_xor(v1, 4, 64);
    if ((lane & 7) == 0) {
        e2s[wv * 8 + (lane >> 3)]      = v0;
        e2s[32 + wv * 8 + (lane >> 3)] = v1;
    }
    __syncthreads();

    // epilogue: C/D layout col = nt*16 + l15, row = quad*4 + reg
    float nlls = 0.f, corr = 0.f;
#pragma unroll
    for (int reg = 0; reg < 4; ++reg) {
        int rloc = wv * 16 + quad * 4 + reg;
        float e2v = e2s[rloc];
        float lg[4];
#pragma unroll
        for (int nt = 0; nt < 4; ++nt) {
            float d2 = e2v + p2[nt * 16 + l15] - 2.f * acc[nt][reg];
            d2 = fmaxf(d2, 1e-12f);
            lg[nt] = -sqrtf(d2);
        }
        float mv = lg[0]; int mc = l15;
#pragma unroll
        for (int nt = 1; nt < 4; ++nt) {
            int cix = nt * 16 + l15;
            if (lg[nt] > mv) { mv = lg[nt]; mc = cix; }
        }
#pragma unroll
        for (int o = 1; o < 16; o <<= 1) {
            float mo = __shfl_xor(mv, o, 64);
            int   co = __shfl_xor(mc, o, 64);
            if (mo > mv || (mo == mv && co < mc)) { mv = mo; mc = co; }
        }
        int lab = labels[rbase + rloc];
        float se = 0.f, ll = 0.f;
#pragma unroll
        for (int nt = 0; nt < 4; ++nt) se += __expf(lg[nt] - mv);
        if ((lab & 15) == l15) ll = lg[lab >> 4];
#pragma unroll
        for (int o = 1; o < 16; o <<= 1) {
            se += __shfl_xor(se, o, 64);
            ll += __shfl_xor(ll, o, 64);
        }
        if (l15 == 0) {
            nlls += __logf(se) + mv - ll;
            corr += (mc == lab) ? 1.f : 0.f;
        }
    }
#pragma unroll
    for (int o = 1; o < 64; o <<= 1) {
        nlls += __shfl_xor(nlls, o, 64);
        corr += __shfl_xor(corr, o, 64);
    }
    if (lane == 0) { rb[wv] = nlls; rb[4 + wv] = corr; }
    __syncthreads();
    if (t == 0) {
        atomicAdd(lossAcc, rb[0] + rb[1] + rb[2] + rb[3]);
        atomicAdd(accAcc, rb[4] + rb[5] + rb[6] + rb[7]);
    }
}

// ---------------- finalize ----------------
__global__ void k_final(const float* __restrict__ lossAcc,
                        const float* __restrict__ accAcc,
                        float* __restrict__ out) {
    if (threadIdx.x == 0 && blockIdx.x == 0) {
        out[0] = lossAcc[0] * (1.f / NROWS);
        out[1] = accAcc[0] * (1.f / NROWS);
    }
}

extern "C" void kernel_launch(void* const* d_in, const int* in_sizes, int n_in,
                              void* d_out, int out_size, void* d_ws, size_t ws_size,
                              hipStream_t stream) {
    const float* emb    = (const float*)d_in[0];
    const int*   labels = (const int*)d_in[1];
    float* out = (float*)d_out;

    float* wsf = (float*)d_ws;
    int*   wsi = (int*)d_ws;
    float*          protoSum = wsf + WS_PROTOSUM;
    int*            cursors  = wsi + WS_CURSORS;
    float*          lossAcc  = wsf + WS_LOSS;
    float*          accAcc   = wsf + WS_ACC;
    float*          p2       = wsf + WS_P2;
    int*            perm     = wsi + WS_PERM;
    unsigned short* pB       = (unsigned short*)(wsf + WS_PB);  // overlays perm

    hipMemsetAsync(d_ws, 0, MEMSET_WORDS * sizeof(int), stream);

    k_scatter<<<NROWS / 256, 256, 0, stream>>>(labels, cursors, perm);
    k_psum<<<NCLS * 32, 256, 0, stream>>>(emb, cursors, perm, protoSum);
    k_protofin<<<NCLS, 512, 0, stream>>>(protoSum, cursors, pB, p2);
    k_logits<<<NROWS / LROWS, 256, 0, stream>>>(emb, labels, pB, p2, lossAcc, accAcc);
    k_final<<<1, 64, 0, stream>>>(lossAcc, accAcc, out);
}